// Round 3
// baseline (452.729 us; speedup 1.0000x reference)
//
#include <hip/hip_runtime.h>

#define IMG   512
#define TW    64
#define TH    32
#define HALO  5
#define WS    11
#define IHH   (TH + 2*HALO)   // 42 rows of h-smoothed data
#define NP    96
#define NSLOT 256

__global__ __launch_bounds__(256, 5) void ssim_main(const float* __restrict__ img1,
                                                    const float* __restrict__ img2,
                                                    double* __restrict__ acc) {
    // 3 signal planes (max of the two passes), row-rotated to kill bank conflicts
    __shared__ float hA[3][IHH * TW];   // 32,256 B -> 5 blocks/CU

    const int tid = threadIdx.x;
    const int bx = blockIdx.x;   // 0..7
    const int by = blockIdx.y;   // 0..15
    const int plane = blockIdx.z;
    const float* p1 = img1 + (size_t)plane * IMG * IMG;
    const float* p2 = img2 + (size_t)plane * IMG * IMG;

    // Gaussian weights (float32, matches jnp within rounding)
    float w[WS];
    {
        float s = 0.f;
        #pragma unroll
        for (int i = 0; i < WS; ++i) {
            float c = (float)(i - HALO) * (1.0f/1.5f);
            w[i] = expf(-0.5f * c * c);
            s += w[i];
        }
        float inv = 1.0f / s;
        #pragma unroll
        for (int i = 0; i < WS; ++i) w[i] *= inv;
    }

    const int c  = tid & 63;            // phase-2 column
    const int r0 = (tid >> 6) << 3;     // phase-2 row base (0,8,16,24)
    const int cc = c + 4 * r0;          // rotated-read base

    float mu1r[8], mu2r[8];             // pass-A results held across pass B

    // =================== PASS A : linear signals x1, x2 ===================
    for (int u = tid; u < IHH * 8; u += 256) {
        const int r  = u >> 3;
        const int ch = u & 7;
        const int gy = by * TH + r - HALO;
        const bool rowOK = (unsigned)gy < IMG;

        float v1[24], v2[24];
        #pragma unroll
        for (int j = 0; j < 6; ++j) {
            const int gx = bx * TW + ch * 8 - 8 + 4 * j;
            float4 a = make_float4(0.f,0.f,0.f,0.f), b = a;
            if (rowOK && (unsigned)gx < IMG) {
                a = *(const float4*)(p1 + (size_t)gy * IMG + gx);
                b = *(const float4*)(p2 + (size_t)gy * IMG + gx);
            }
            v1[4*j+0]=a.x; v1[4*j+1]=a.y; v1[4*j+2]=a.z; v1[4*j+3]=a.w;
            v2[4*j+0]=b.x; v2[4*j+1]=b.y; v2[4*j+2]=b.z; v2[4*j+3]=b.w;
        }

        float a1[8], a2[8];
        #pragma unroll
        for (int o = 0; o < 8; ++o) { a1[o]=0.f; a2[o]=0.f; }
        #pragma unroll
        for (int i = 3; i <= 20; ++i) {
            const float x1 = v1[i], x2 = v2[i];
            #pragma unroll
            for (int o = 0; o < 8; ++o) {
                const int t = i - 3 - o;
                if (t >= 0 && t < WS) { a1[o] += w[t]*x1; a2[o] += w[t]*x2; }
            }
        }

        // rotated write: tile col x stored at (x + 4r) & 63 within the row
        const int xs0 = (ch*8     + 4*r) & 63;
        const int xs1 = (ch*8 + 4 + 4*r) & 63;
        float* row0 = &hA[0][r * TW];
        float* row1 = &hA[1][r * TW];
        *(float4*)(row0 + xs0) = make_float4(a1[0],a1[1],a1[2],a1[3]);
        *(float4*)(row0 + xs1) = make_float4(a1[4],a1[5],a1[6],a1[7]);
        *(float4*)(row1 + xs0) = make_float4(a2[0],a2[1],a2[2],a2[3]);
        *(float4*)(row1 + xs1) = make_float4(a2[4],a2[5],a2[6],a2[7]);
    }
    __syncthreads();

    {   // vertical conv for mu1, mu2 -> registers
        float m1[8], m2[8];
        #pragma unroll
        for (int o = 0; o < 8; ++o) { m1[o]=0.f; m2[o]=0.f; }
        #pragma unroll
        for (int k = 0; k < 18; ++k) {
            const int off = (r0 + k) * TW + ((cc + 4*k) & 63);
            const float h1 = hA[0][off];
            const float h2 = hA[1][off];
            #pragma unroll
            for (int o = 0; o < 8; ++o) {
                const int t = k - o;
                if (t >= 0 && t < WS) { m1[o] += w[t]*h1; m2[o] += w[t]*h2; }
            }
        }
        #pragma unroll
        for (int o = 0; o < 8; ++o) { mu1r[o] = m1[o]; mu2r[o] = m2[o]; }
    }
    __syncthreads();

    // =================== PASS B : quadratic signals =======================
    for (int u = tid; u < IHH * 8; u += 256) {
        const int r  = u >> 3;
        const int ch = u & 7;
        const int gy = by * TH + r - HALO;
        const bool rowOK = (unsigned)gy < IMG;

        float v1[24], v2[24];
        #pragma unroll
        for (int j = 0; j < 6; ++j) {
            const int gx = bx * TW + ch * 8 - 8 + 4 * j;
            float4 a = make_float4(0.f,0.f,0.f,0.f), b = a;
            if (rowOK && (unsigned)gx < IMG) {
                a = *(const float4*)(p1 + (size_t)gy * IMG + gx);
                b = *(const float4*)(p2 + (size_t)gy * IMG + gx);
            }
            v1[4*j+0]=a.x; v1[4*j+1]=a.y; v1[4*j+2]=a.z; v1[4*j+3]=a.w;
            v2[4*j+0]=b.x; v2[4*j+1]=b.y; v2[4*j+2]=b.z; v2[4*j+3]=b.w;
        }

        float a11[8], a22[8], a12[8];
        #pragma unroll
        for (int o = 0; o < 8; ++o) { a11[o]=0.f; a22[o]=0.f; a12[o]=0.f; }
        #pragma unroll
        for (int i = 3; i <= 20; ++i) {
            const float x1 = v1[i], x2 = v2[i];
            const float q11 = x1*x1, q22 = x2*x2, q12 = x1*x2;
            #pragma unroll
            for (int o = 0; o < 8; ++o) {
                const int t = i - 3 - o;
                if (t >= 0 && t < WS) {
                    a11[o] += w[t]*q11; a22[o] += w[t]*q22; a12[o] += w[t]*q12;
                }
            }
        }

        const int xs0 = (ch*8     + 4*r) & 63;
        const int xs1 = (ch*8 + 4 + 4*r) & 63;
        float* row0 = &hA[0][r * TW];
        float* row1 = &hA[1][r * TW];
        float* row2 = &hA[2][r * TW];
        *(float4*)(row0 + xs0) = make_float4(a11[0],a11[1],a11[2],a11[3]);
        *(float4*)(row0 + xs1) = make_float4(a11[4],a11[5],a11[6],a11[7]);
        *(float4*)(row1 + xs0) = make_float4(a22[0],a22[1],a22[2],a22[3]);
        *(float4*)(row1 + xs1) = make_float4(a22[4],a22[5],a22[6],a22[7]);
        *(float4*)(row2 + xs0) = make_float4(a12[0],a12[1],a12[2],a12[3]);
        *(float4*)(row2 + xs1) = make_float4(a12[4],a12[5],a12[6],a12[7]);
    }
    __syncthreads();

    const float C1 = 0.01f*0.01f, C2 = 0.03f*0.03f;
    float lsum = 0.f;
    {
        float m11[8], m22[8], m12[8];
        #pragma unroll
        for (int o = 0; o < 8; ++o) { m11[o]=0.f; m22[o]=0.f; m12[o]=0.f; }
        #pragma unroll
        for (int k = 0; k < 18; ++k) {
            const int off = (r0 + k) * TW + ((cc + 4*k) & 63);
            const float h11 = hA[0][off];
            const float h22 = hA[1][off];
            const float h12 = hA[2][off];
            #pragma unroll
            for (int o = 0; o < 8; ++o) {
                const int t = k - o;
                if (t >= 0 && t < WS) {
                    m11[o] += w[t]*h11; m22[o] += w[t]*h22; m12[o] += w[t]*h12;
                }
            }
        }
        #pragma unroll
        for (int o = 0; o < 8; ++o) {
            const float mu1 = mu1r[o], mu2 = mu2r[o];
            const float mu1s = mu1*mu1, mu2s = mu2*mu2, mu12 = mu1*mu2;
            const float s11 = m11[o] - mu1s;
            const float s22 = m22[o] - mu2s;
            const float s12 = m12[o] - mu12;
            const float num = (2.f*mu12 + C1) * (2.f*s12 + C2);
            const float den = (mu1s + mu2s + C1) * (s11 + s22 + C2);
            lsum += num / den;
        }
    }

    // wave reduce + block reduce + spread atomic
    #pragma unroll
    for (int d = 32; d >= 1; d >>= 1)
        lsum += __shfl_down(lsum, d, 64);
    __shared__ float wsum[4];
    if ((tid & 63) == 0) wsum[tid >> 6] = lsum;
    __syncthreads();
    if (tid == 0) {
        const float t = wsum[0] + wsum[1] + wsum[2] + wsum[3];
        const int slot = (blockIdx.z * 128 + blockIdx.y * 8 + blockIdx.x) & (NSLOT - 1);
        atomicAdd(&acc[slot], (double)t);
    }
}

__global__ void ssim_final(const double* __restrict__ acc, float* __restrict__ out) {
    const int l = threadIdx.x;   // 64 threads
    double s = acc[l] + acc[l + 64] + acc[l + 128] + acc[l + 192];
    #pragma unroll
    for (int d = 32; d >= 1; d >>= 1)
        s += __shfl_down(s, d, 64);
    if (l == 0)
        out[0] = 1.0f - (float)(s / (double)((size_t)NP * IMG * IMG));
}

extern "C" void kernel_launch(void* const* d_in, const int* in_sizes, int n_in,
                              void* d_out, int out_size, void* d_ws, size_t ws_size,
                              hipStream_t stream) {
    const float* img1 = (const float*)d_in[0];
    const float* img2 = (const float*)d_in[1];
    float* out = (float*)d_out;
    double* acc = (double*)d_ws;

    hipMemsetAsync(d_ws, 0, NSLOT * sizeof(double), stream);

    dim3 grid(IMG / TW, IMG / TH, NP);
    ssim_main<<<grid, dim3(256), 0, stream>>>(img1, img2, acc);
    ssim_final<<<1, dim3(64), 0, stream>>>(acc, out);
}

// Round 4
// 131.013 us; speedup vs baseline: 3.4556x; 3.4556x over previous
//
#include <hip/hip_runtime.h>

#define IMG   512
#define TW    32
#define TH    32
#define HALO  5
#define WS    11
#define IHH   (TH + 2*HALO)   // 42
#define NP    96
#define NSLOT 256

// Gaussian window, sigma=1.5, ws=11: computed in double, rounded to f32.
// Matches the jnp float32 computation to ~1 ulp (threshold is 2e-2).
__device__ __constant__ float const_dummy;  // (no-op, keeps nothing alive)

__global__ __launch_bounds__(256, 8) void ssim_main(const float* __restrict__ img1,
                                                    const float* __restrict__ img2,
                                                    double* __restrict__ acc) {
    constexpr float W[WS] = {
        0.00102837990674f, 0.00759883148699f, 0.03600079242909f,
        0.10936069869137f, 0.21300538108707f, 0.26601190869814f,
        0.21300538108707f, 0.10936069869137f, 0.03600079242909f,
        0.00759883148699f, 0.00102837990674f };

    __shared__ float hA[5][IHH * TW];   // 26,880 B -> 6 blocks/CU

    const int tid = threadIdx.x;
    const int bx = blockIdx.x;   // 0..15
    const int by = blockIdx.y;   // 0..15
    const float* p1 = img1 + (size_t)blockIdx.z * IMG * IMG;
    const float* p2 = img2 + (size_t)blockIdx.z * IMG * IMG;

    // ---------- Phase 1: horizontal conv, global -> registers -> hA --------
    // unit = (padded row r, 4-wide chunk ch). 42*8 = 336 units.
    for (int u = tid; u < IHH * 8; u += 256) {
        const int r  = u >> 3;        // 0..41
        const int ch = u & 7;         // 0..7 (4-wide chunks)
        const int gy = by * TH + r - HALO;
        const bool rowOK = (unsigned)gy < IMG;
        const float* r1 = p1 + (size_t)gy * IMG;
        const float* r2 = p2 + (size_t)gy * IMG;

        float a1[4]  = {0.f,0.f,0.f,0.f};
        float a2[4]  = {0.f,0.f,0.f,0.f};
        float a11[4] = {0.f,0.f,0.f,0.f};
        float a22[4] = {0.f,0.f,0.f,0.f};
        float a12[4] = {0.f,0.f,0.f,0.f};

        // streaming: one float4-pair in flight at a time (low VGPR pressure)
        #pragma unroll
        for (int j = 0; j < 5; ++j) {
            const int gx = bx * TW + ch * 4 - 8 + 4 * j;
            float4 A = make_float4(0.f,0.f,0.f,0.f), B = A;
            if (rowOK && (unsigned)gx < IMG) {
                A = *(const float4*)(r1 + gx);
                B = *(const float4*)(r2 + gx);
            }
            const float e1[4] = {A.x, A.y, A.z, A.w};
            const float e2[4] = {B.x, B.y, B.z, B.w};
            #pragma unroll
            for (int e = 0; e < 4; ++e) {
                const int i = 4*j + e;              // 0..19; taps live in 3..16
                const float x1 = e1[e], x2 = e2[e];
                const float q11 = x1*x1, q22 = x2*x2, q12 = x1*x2;
                #pragma unroll
                for (int o = 0; o < 4; ++o) {
                    const int t = i - 3 - o;
                    if (t >= 0 && t < WS) {
                        a1[o]  += W[t]*x1;  a2[o]  += W[t]*x2;
                        a11[o] += W[t]*q11; a22[o] += W[t]*q22; a12[o] += W[t]*q12;
                    }
                }
            }
        }

        // XOR-swizzled write: cols ch*4..ch*4+3 -> words (ch*4)^rot .. +3
        const int wd = (ch * 4) ^ ((r & 7) << 2);
        float* dst = &hA[0][r * TW + wd];
        const int ss = IHH * TW;
        *(float4*)(dst)        = make_float4(a1[0],a1[1],a1[2],a1[3]);
        *(float4*)(dst + ss)   = make_float4(a2[0],a2[1],a2[2],a2[3]);
        *(float4*)(dst + 2*ss) = make_float4(a11[0],a11[1],a11[2],a11[3]);
        *(float4*)(dst + 3*ss) = make_float4(a22[0],a22[1],a22[2],a22[3]);
        *(float4*)(dst + 4*ss) = make_float4(a12[0],a12[1],a12[2],a12[3]);
    }
    __syncthreads();

    // ---------- Phase 2: vertical conv + SSIM ------------------------------
    const float C1 = 0.01f*0.01f, C2 = 0.03f*0.03f;
    float lsum = 0.f;
    {
        const int c  = tid & 31;
        const int r0 = (tid >> 5) << 2;   // 0,4,...,28
        float m1[4]  = {0.f,0.f,0.f,0.f};
        float m2[4]  = {0.f,0.f,0.f,0.f};
        float m11[4] = {0.f,0.f,0.f,0.f};
        float m22[4] = {0.f,0.f,0.f,0.f};
        float m12[4] = {0.f,0.f,0.f,0.f};

        #pragma unroll
        for (int k = 0; k < 14; ++k) {
            const int row = r0 + k;
            const int off = row * TW + (c ^ ((row & 7) << 2));
            const float h1  = hA[0][off];
            const float h2  = hA[1][off];
            const float h11 = hA[2][off];
            const float h22 = hA[3][off];
            const float h12 = hA[4][off];
            #pragma unroll
            for (int o = 0; o < 4; ++o) {
                const int t = k - o;
                if (t >= 0 && t < WS) {
                    m1[o]  += W[t]*h1;  m2[o]  += W[t]*h2;
                    m11[o] += W[t]*h11; m22[o] += W[t]*h22; m12[o] += W[t]*h12;
                }
            }
        }

        #pragma unroll
        for (int o = 0; o < 4; ++o) {
            const float mu1 = m1[o], mu2 = m2[o];
            const float mu1s = mu1*mu1, mu2s = mu2*mu2, mu12 = mu1*mu2;
            const float s11 = m11[o] - mu1s;
            const float s22 = m22[o] - mu2s;
            const float s12 = m12[o] - mu12;
            const float num = (2.f*mu12 + C1) * (2.f*s12 + C2);
            const float den = (mu1s + mu2s + C1) * (s11 + s22 + C2);
            lsum += num / den;
        }
    }

    // wave reduce + block reduce + spread atomic
    #pragma unroll
    for (int d = 32; d >= 1; d >>= 1)
        lsum += __shfl_down(lsum, d, 64);
    __shared__ float wsum[4];
    if ((tid & 63) == 0) wsum[tid >> 6] = lsum;
    __syncthreads();
    if (tid == 0) {
        const float t = wsum[0] + wsum[1] + wsum[2] + wsum[3];
        const int slot = (blockIdx.z * 256 + blockIdx.y * 16 + blockIdx.x) & (NSLOT - 1);
        atomicAdd(&acc[slot], (double)t);
    }
}

__global__ void ssim_final(const double* __restrict__ acc, float* __restrict__ out) {
    const int l = threadIdx.x;   // 64 threads
    double s = acc[l] + acc[l + 64] + acc[l + 128] + acc[l + 192];
    #pragma unroll
    for (int d = 32; d >= 1; d >>= 1)
        s += __shfl_down(s, d, 64);
    if (l == 0)
        out[0] = 1.0f - (float)(s / (double)((size_t)NP * IMG * IMG));
}

extern "C" void kernel_launch(void* const* d_in, const int* in_sizes, int n_in,
                              void* d_out, int out_size, void* d_ws, size_t ws_size,
                              hipStream_t stream) {
    const float* img1 = (const float*)d_in[0];
    const float* img2 = (const float*)d_in[1];
    float* out = (float*)d_out;
    double* acc = (double*)d_ws;

    hipMemsetAsync(d_ws, 0, NSLOT * sizeof(double), stream);

    dim3 grid(IMG / TW, IMG / TH, NP);
    ssim_main<<<grid, dim3(256), 0, stream>>>(img1, img2, acc);
    ssim_final<<<1, dim3(64), 0, stream>>>(acc, out);
}

// Round 5
// 116.373 us; speedup vs baseline: 3.8903x; 1.1258x over previous
//
#include <hip/hip_runtime.h>

#define IMG   512
#define TW    32
#define TH    32
#define HALO  5
#define WS    11
#define IHH   42
#define LDW   36                 // padded LDS row stride in words (bank = 4r+c, conflict-free)
#define SIGSZ (IHH*LDW)          // 1512 words per signal plane
#define NP    96
#define NSLOT 256

__global__ __launch_bounds__(256, 5) void ssim_main(const float* __restrict__ img1,
                                                    const float* __restrict__ img2,
                                                    double* __restrict__ acc) {
    constexpr float W[WS] = {
        0.00102837990674f, 0.00759883148699f, 0.03600079242909f,
        0.10936069869137f, 0.21300538108707f, 0.26601190869814f,
        0.21300538108707f, 0.10936069869137f, 0.03600079242909f,
        0.00759883148699f, 0.00102837990674f };

    __shared__ float hA[5 * SIGSZ];   // 30,240 B -> 5 blocks/CU

    const int tid = threadIdx.x;
    const int bx = blockIdx.x;   // 0..15
    const int by = blockIdx.y;   // 0..15
    const float* p1 = img1 + (size_t)blockIdx.z * (IMG*IMG);
    const float* p2 = img2 + (size_t)blockIdx.z * (IMG*IMG);

    // ---------- Phase 1: horizontal conv, 8-wide chunks, 168 units ----------
    if (tid < IHH * 4) {
        const int r  = tid >> 2;      // 0..41 padded row
        const int ch = tid & 3;       // 0..3  (8-wide col chunk)
        const int gy = by * TH + r - HALO;
        const bool rowOK = (unsigned)gy < IMG;
        const float* r1 = p1 + (size_t)gy * IMG;
        const float* r2 = p2 + (size_t)gy * IMG;

        float a1[8], a2[8], a11[8], a22[8], a12[8];
        #pragma unroll
        for (int o = 0; o < 8; ++o) { a1[o]=0.f; a2[o]=0.f; a11[o]=0.f; a22[o]=0.f; a12[o]=0.f; }

        #pragma unroll
        for (int j = 0; j < 6; ++j) {
            const int gx = bx * TW + ch * 8 - 8 + 4 * j;
            float4 A = make_float4(0.f,0.f,0.f,0.f), B = A;
            if (rowOK && (unsigned)gx < IMG) {
                A = *(const float4*)(r1 + gx);
                B = *(const float4*)(r2 + gx);
            }
            const float e1[4] = {A.x,A.y,A.z,A.w};
            const float e2[4] = {B.x,B.y,B.z,B.w};
            #pragma unroll
            for (int e = 0; e < 4; ++e) {
                const int i = 4*j + e;                 // taps live in 3..20
                if (i < 3 || i > 20) continue;
                const float x1 = e1[e], x2 = e2[e];
                const float q11 = x1*x1, q22 = x2*x2, q12 = x1*x2;
                #pragma unroll
                for (int o = 0; o < 8; ++o) {
                    const int t = i - 3 - o;
                    if (t >= 0 && t < WS) {
                        a1[o]  += W[t]*x1;  a2[o]  += W[t]*x2;
                        a11[o] += W[t]*q11; a22[o] += W[t]*q22; a12[o] += W[t]*q12;
                    }
                }
            }
        }

        const int wb = r * LDW + ch * 8;
        *(float4*)&hA[0*SIGSZ + wb]     = make_float4(a1[0],a1[1],a1[2],a1[3]);
        *(float4*)&hA[0*SIGSZ + wb + 4] = make_float4(a1[4],a1[5],a1[6],a1[7]);
        *(float4*)&hA[1*SIGSZ + wb]     = make_float4(a2[0],a2[1],a2[2],a2[3]);
        *(float4*)&hA[1*SIGSZ + wb + 4] = make_float4(a2[4],a2[5],a2[6],a2[7]);
        *(float4*)&hA[2*SIGSZ + wb]     = make_float4(a11[0],a11[1],a11[2],a11[3]);
        *(float4*)&hA[2*SIGSZ + wb + 4] = make_float4(a11[4],a11[5],a11[6],a11[7]);
        *(float4*)&hA[3*SIGSZ + wb]     = make_float4(a22[0],a22[1],a22[2],a22[3]);
        *(float4*)&hA[3*SIGSZ + wb + 4] = make_float4(a22[4],a22[5],a22[6],a22[7]);
        *(float4*)&hA[4*SIGSZ + wb]     = make_float4(a12[0],a12[1],a12[2],a12[3]);
        *(float4*)&hA[4*SIGSZ + wb + 4] = make_float4(a12[4],a12[5],a12[6],a12[7]);
    }
    __syncthreads();

    // ---------- Phase 2: vertical conv (ds_read2-friendly) + SSIM ----------
    const int c  = tid & 31;
    const int r0 = (tid >> 5) << 2;   // 0,4,...,28
    float m[5][4];
    #pragma unroll
    for (int s = 0; s < 5; ++s)
        #pragma unroll
        for (int o = 0; o < 4; ++o) m[s][o] = 0.f;

    #pragma unroll
    for (int s = 0; s < 5; ++s) {
        // opaque base per signal: keeps paired offsets <= 255 dwords so the
        // compiler merges row-pairs into ds_read2_b32
        int off = s * SIGSZ + r0 * LDW + c;
        asm("" : "+v"(off));
        #pragma unroll
        for (int k = 0; k < 8; ++k) {
            const float h = hA[off + k * LDW];
            #pragma unroll
            for (int o = 0; o < 4; ++o) {
                const int t = k - o;
                if (t >= 0 && t < WS) m[s][o] += W[t] * h;
            }
        }
        int off2 = off + 8 * LDW;
        asm("" : "+v"(off2));
        #pragma unroll
        for (int k = 8; k < 14; ++k) {
            const float h = hA[off2 + (k - 8) * LDW];
            #pragma unroll
            for (int o = 0; o < 4; ++o) {
                const int t = k - o;
                if (t >= 0 && t < WS) m[s][o] += W[t] * h;
            }
        }
    }

    const float C1 = 0.01f*0.01f, C2 = 0.03f*0.03f;
    float lsum = 0.f;
    #pragma unroll
    for (int o = 0; o < 4; ++o) {
        const float mu1 = m[0][o], mu2 = m[1][o];
        const float mu1s = mu1*mu1, mu2s = mu2*mu2, mu12 = mu1*mu2;
        const float s11 = m[2][o] - mu1s;
        const float s22 = m[3][o] - mu2s;
        const float s12 = m[4][o] - mu12;
        const float num = (2.f*mu12 + C1) * (2.f*s12 + C2);
        const float den = (mu1s + mu2s + C1) * (s11 + s22 + C2);
        lsum += num * __builtin_amdgcn_rcpf(den);
    }

    // wave reduce + block reduce + spread atomic
    #pragma unroll
    for (int d = 32; d >= 1; d >>= 1)
        lsum += __shfl_down(lsum, d, 64);
    __shared__ float wsum[4];
    if ((tid & 63) == 0) wsum[tid >> 6] = lsum;
    __syncthreads();
    if (tid == 0) {
        const float t = wsum[0] + wsum[1] + wsum[2] + wsum[3];
        const int slot = (blockIdx.z * 256 + blockIdx.y * 16 + blockIdx.x) & (NSLOT - 1);
        atomicAdd(&acc[slot], (double)t);
    }
}

__global__ void ssim_final(const double* __restrict__ acc, float* __restrict__ out) {
    const int l = threadIdx.x;   // 64 threads
    double s = acc[l] + acc[l + 64] + acc[l + 128] + acc[l + 192];
    #pragma unroll
    for (int d = 32; d >= 1; d >>= 1)
        s += __shfl_down(s, d, 64);
    if (l == 0)
        out[0] = 1.0f - (float)(s / (double)((size_t)NP * IMG * IMG));
}

extern "C" void kernel_launch(void* const* d_in, const int* in_sizes, int n_in,
                              void* d_out, int out_size, void* d_ws, size_t ws_size,
                              hipStream_t stream) {
    const float* img1 = (const float*)d_in[0];
    const float* img2 = (const float*)d_in[1];
    float* out = (float*)d_out;
    double* acc = (double*)d_ws;

    hipMemsetAsync(d_ws, 0, NSLOT * sizeof(double), stream);

    dim3 grid(IMG / TW, IMG / TH, NP);
    ssim_main<<<grid, dim3(256), 0, stream>>>(img1, img2, acc);
    ssim_final<<<1, dim3(64), 0, stream>>>(acc, out);
}